// Round 12
// baseline (151.410 us; speedup 1.0000x reference)
//
#include <hip/hip_runtime.h>
#include <math.h>

#define T_SEQ 4096
#define NBATCH 4
#define NEMBD 1024
#define HS 64
#define BT (NBATCH * T_SEQ)   // 16384

typedef float f32x4 __attribute__((ext_vector_type(4)));
typedef short s8v  __attribute__((ext_vector_type(8)));   // 8 x bf16 bits
typedef short s4v  __attribute__((ext_vector_type(4)));   // 4 x bf16 bits

__device__ __forceinline__ short f2b_rne(float f) {
    union { float f; unsigned u; } v; v.f = f;
    unsigned r = v.u + 0x7fffu + ((v.u >> 16) & 1u);
    return (short)(r >> 16);
}
// pack 2 fp32 -> 2 bf16 (truncate) in one v_perm
__device__ __forceinline__ unsigned pk2(float lo, float hi) {
    return __builtin_amdgcn_perm(__float_as_uint(hi), __float_as_uint(lo), 0x07060302u);
}

// ---------------------------------------------------------------------------
// FINAL CONFIGURATION (R22 = R21 verbatim, session best 151.38us).
// Pipeline: wtrans (2.5us) -> proj fp32-direct, LDS-dbuf, 1 barrier/step
// (~19us) -> attn R0/R10 structure (41.4us).  Harness poison fills (~83us)
// dominate the remainder and are outside kernel control.
//
// Session ledger (what was tried and what it proved):
//  R11 kt-split + HBM partials:   65us  — partial-store traffic kills it
//  R12 cross-tile K reg-prefetch: 72us  — compiler spills >128-VGPR live set
//  R13/14 fused-pair lambdas:    116us  — lambda live-state spills; 1 blk/CU
//  R15 wide block (1024,8):      108us  — reg cap 64 -> 370MB scratch spill
//  R16 wide block (1024,4):       81us  — 1024-thread regalloc still spills
//  R17 q-split (clean, no spill): 83us  — exactly 2x tiles -> 2x time
//  => attn law: time = tile-iterations x ~1535 cyc*CU, invariant to
//     per-tile MFMA width, occupancy, and memory traffic.  The R10 config
//     (512 blk x 8 waves, 16640 tiles, 64 VGPR, 36KB LDS) is the floor.
//  R18/19 xcast deleted (in-staging cast): 153.1us (-6.6)
//  R20 W reg-dbuf from L2:       176us  — compiler DROPS reg prefetch
//     (VGPR_Count=40) -> serial L2 latency; never hold prefetch in regs
//     across phases, sink to LDS instead.
//  R21 proj LDS-dbuf 1-barrier:  151.4us (-1.7)
// ---------------------------------------------------------------------------

// ---------------------------------------------------------------------------
// Kernel 1: W{q,k,v} [1024x64] fp32 -> Wt[192][1024] bf16 transposed.
// Softmax scale C^-0.5 * log2(e) folded into Wq.
// ---------------------------------------------------------------------------
__global__ __launch_bounds__(256) void wtrans_kernel(
        const float* __restrict__ Wq, const float* __restrict__ Wk,
        const float* __restrict__ Wv, short* __restrict__ Wt) {
    int e = blockIdx.x * 256 + threadIdx.x;
    int col = e & 63, k = (e >> 6) & 1023, mat = e >> 16;
    const float* W = (mat == 0) ? Wq : ((mat == 1) ? Wk : Wv);
    float scale = (mat == 0) ? 0.0450842298f : 1.0f;   // 2^-5 * log2(e)
    Wt[(size_t)(mat * 64 + col) * 1024 + k] = f2b_rne(W[k * 64 + col] * scale);
}

// ---------------------------------------------------------------------------
// Kernel 2: projections — R19 dataflow + LDS double-buffer (R21).
// fp32 x read directly (cast rides the staging load); W and x prefetched
// into regs then immediately sunk to LDS (the only prefetch pattern the
// compiler preserves); xs[2]/wsh[2] double-buffer -> ONE barrier per 64-k
// step.  Single-barrier safety: a wave re-writes buffer b only after
// passing a barrier that every reader of b has already passed.
// ---------------------------------------------------------------------------
__global__ __launch_bounds__(512) void proj_kernel(
        const float* __restrict__ xf, const short* __restrict__ Wt,
        short* __restrict__ QKV) {
    __shared__ short xs[2][32 * 72];
    __shared__ short wsh[2][192 * 72];
    int tid = threadIdx.x;
    int w = tid >> 6, l = tid & 63, quad = l >> 4, c16 = l & 15;
    int rt = w >> 2, cg = w & 3;
    int row0 = blockIdx.x * 32;
    short* VpT = QKV + 2 * (size_t)BT * HS;   // tiled [b][kt][64 d][64 key]

    int xrow = tid >> 4, xc4 = (tid & 15) * 4;

    s8v  wreg[3];
    float4 xreg;
    #pragma unroll
    for (int i = 0; i < 3; i++) {
        int c = tid + 512 * i;
        wreg[i] = *(const s8v*)(Wt + (size_t)(c >> 3) * 1024 + ((c & 7) * 8));
    }
    xreg = *(const float4*)(xf + (size_t)(row0 + xrow) * 1024 + xc4);

    f32x4 acc[3] = {};
    int buf = 0;
    for (int ko = 0; ko < NEMBD; ko += 64, buf ^= 1) {
        // ---- stage prefetched regs into LDS buffer `buf` ----
        #pragma unroll
        for (int i = 0; i < 3; i++) {
            int c = tid + 512 * i;
            *(s8v*)(&wsh[buf][(c >> 3) * 72 + ((c & 7) * 8)]) = wreg[i];
        }
        {
            union { s4v v; unsigned u[2]; } pkv;
            pkv.u[0] = pk2(xreg.x, xreg.y);
            pkv.u[1] = pk2(xreg.z, xreg.w);
            *(s4v*)(&xs[buf][xrow * 72 + xc4]) = pkv.v;
        }
        __syncthreads();
        // ---- prefetch next step's x/W into registers (sunk to LDS next) --
        {
            int kn = (ko + 64 < NEMBD) ? (ko + 64) : 0;
            #pragma unroll
            for (int i = 0; i < 3; i++) {
                int c = tid + 512 * i;
                wreg[i] = *(const s8v*)(Wt + (size_t)(c >> 3) * 1024 + kn + ((c & 7) * 8));
            }
            xreg = *(const float4*)(xf + (size_t)(row0 + xrow) * 1024 + kn + xc4);
        }
        // ---- MFMAs on buffer `buf` ----
        #pragma unroll
        for (int ks = 0; ks < 2; ks++) {
            s8v a = *(const s8v*)(&xs[buf][(rt * 16 + c16) * 72 + ks * 32 + quad * 8]);
            #pragma unroll
            for (int j = 0; j < 3; j++) {
                s8v b = *(const s8v*)(&wsh[buf][(cg * 48 + j * 16 + c16) * 72 + ks * 32 + quad * 8]);
                acc[j] = __builtin_amdgcn_mfma_f32_16x16x32_bf16(a, b, acc[j], 0, 0, 0);
            }
        }
        // no trailing barrier: next step writes the OTHER buffer
    }

    // ---- epilogue ----
    #pragma unroll
    for (int j = 0; j < 3; j++) {
        int g = cg * 48 + j * 16 + c16;
        int mat = g >> 6, h = g & 63;
        if (mat < 2) {
            #pragma unroll
            for (int r = 0; r < 4; r++) {
                int row = row0 + rt * 16 + quad * 4 + r;
                QKV[(size_t)mat * BT * HS + (size_t)row * HS + h] = f2b_rne(acc[j][r]);
            }
        } else {
            int tg = row0 + rt * 16 + quad * 4;
            int b = tg >> 12, t = tg & 4095;
            size_t base = (((size_t)((b * 64 + (t >> 6)) * 64 + h)) << 6) + (t & 63);
            s4v pv;
            #pragma unroll
            for (int r = 0; r < 4; r++) pv[r] = f2b_rne(acc[j][r]);
            *(s4v*)(VpT + base) = pv;
        }
    }
}

// ---------------------------------------------------------------------------
// Kernel 3: causal flash attention — R0/R10 kernel VERBATIM (proven 41.4us).
// ---------------------------------------------------------------------------
__global__ __launch_bounds__(512, 4) void attn_kernel(
        const short* __restrict__ QKV, float* __restrict__ out) {
    __shared__ float smem[9216];   // 36 KB: P regions; epilogue overlays
    short* Ps = (short*)smem;

    int tid = threadIdx.x;
    int w = tid >> 6, l = tid & 63, quad = l >> 4, c16 = l & 15;
    int bi = blockIdx.x;
    int b  = (bi & 7) >> 1;                 // XCD-affine batch
    int r8 = bi >> 3;                       // 0..63
    int p  = bi & 1;
    int jt = (r8 < 32) ? (127 - (2 * r8 + p)) : (2 * (r8 - 32) + p);
    int q0 = jt * 32;

    const short* Qp  = QKV;
    const short* Kp  = QKV + (size_t)BT * HS;
    const short* VpT = QKV + 2 * (size_t)BT * HS;   // tiled
    size_t bT = (size_t)b * T_SEQ;

    s8v qf[2][2];
    #pragma unroll
    for (int qt = 0; qt < 2; qt++)
        #pragma unroll
        for (int h = 0; h < 2; h++)
            qf[qt][h] = *(const s8v*)(Qp + (bT + q0 + qt * 16 + c16) * HS + h * 32 + quad * 8);

    f32x4 o[2][4] = {};
    float lsum[2] = {0.f, 0.f};
    int nkt = (q0 >> 6) + 1;
    short* Pw[2] = { Ps + (w * 2) * 1152, Ps + (w * 2 + 1) * 1152 };
    const short* kbase = Kp + (bT + c16) * HS + quad * 8;
    const short* vbase = VpT + (((size_t)((b * 64) * 64 + c16)) << 6) + quad * 8;

    for (int kt = w; kt < nkt; kt += 8) {
        int kb = kt * 64;
        bool last = (kt == nkt - 1);

        // ---- phase 1: issue ALL K fragment loads (8 x b128, one wait) ----
        s8v kf[4][2];
        #pragma unroll
        for (int nt = 0; nt < 4; nt++) {
            const short* kr = kbase + (size_t)(kb + nt * 16) * HS;
            kf[nt][0] = *(const s8v*)kr;
            kf[nt][1] = *(const s8v*)(kr + 32);
        }
        // ---- phase 2: S^T = K * Q^T ----
        f32x4 st[2][4];
        #pragma unroll
        for (int nt = 0; nt < 4; nt++) {
            f32x4 z0 = {0.f, 0.f, 0.f, 0.f}, z1 = {0.f, 0.f, 0.f, 0.f};
            z0 = __builtin_amdgcn_mfma_f32_16x16x32_bf16(kf[nt][0], qf[0][0], z0, 0, 0, 0);
            z0 = __builtin_amdgcn_mfma_f32_16x16x32_bf16(kf[nt][1], qf[0][1], z0, 0, 0, 0);
            z1 = __builtin_amdgcn_mfma_f32_16x16x32_bf16(kf[nt][0], qf[1][0], z1, 0, 0, 0);
            z1 = __builtin_amdgcn_mfma_f32_16x16x32_bf16(kf[nt][1], qf[1][1], z1, 0, 0, 0);
            st[0][nt] = z0; st[1][nt] = z1;
        }
        // ---- phase 3: issue ALL V fragment loads (hidden by softmax) ----
        s8v vf[4][2];
        #pragma unroll
        for (int nt = 0; nt < 4; nt++) {
            const short* vr = vbase + (((size_t)(kt * 64 + nt * 16)) << 6);
            vf[nt][0] = *(const s8v*)vr;
            vf[nt][1] = *(const s8v*)(vr + 32);
        }
        // ---- phase 4: exp2, diag mask, lsum, pack P -> LDS ----
        #pragma unroll
        for (int qt = 0; qt < 2; qt++) {
            int qrow = q0 + qt * 16 + c16;
            #pragma unroll
            for (int nt = 0; nt < 4; nt++) {
                float pr[4];
                #pragma unroll
                for (int rr = 0; rr < 4; rr++) {
                    float v = st[qt][nt][rr];
                    if (last && (kb + nt * 16 + quad * 4 + rr > qrow)) v = -30000.f;
                    pr[rr] = __builtin_amdgcn_exp2f(v);
                    lsum[qt] += pr[rr];
                }
                union { s4v v; unsigned u[2]; } pkv;
                pkv.u[0] = pk2(pr[0], pr[1]); pkv.u[1] = pk2(pr[2], pr[3]);
                *(s4v*)(Pw[qt] + c16 * 72 + nt * 16 + quad * 4) = pkv.v;
            }
        }
        // ---- phase 5: P A-frags from LDS; phase 6: PV MFMAs ----
        s8v pa[2][2];
        #pragma unroll
        for (int qt = 0; qt < 2; qt++) {
            pa[qt][0] = *(const s8v*)(Pw[qt] + c16 * 72 + quad * 8);
            pa[qt][1] = *(const s8v*)(Pw[qt] + c16 * 72 + quad * 8 + 32);
        }
        #pragma unroll
        for (int nt = 0; nt < 4; nt++)
            #pragma unroll
            for (int qt = 0; qt < 2; qt++) {
                o[qt][nt] = __builtin_amdgcn_mfma_f32_16x16x32_bf16(pa[qt][0], vf[nt][0], o[qt][nt], 0, 0, 0);
                o[qt][nt] = __builtin_amdgcn_mfma_f32_16x16x32_bf16(pa[qt][1], vf[nt][1], o[qt][nt], 0, 0, 0);
            }
    }

    #pragma unroll
    for (int qt = 0; qt < 2; qt++) {
        lsum[qt] += __shfl_xor(lsum[qt], 16);
        lsum[qt] += __shfl_xor(lsum[qt], 32);
    }

    // two-phase per-lane merge (R5 fix)
    #pragma unroll
    for (int qt = 0; qt < 2; qt++) {
        __syncthreads();
        #pragma unroll
        for (int nt = 0; nt < 4; nt++)
            *(f32x4*)(smem + ((w * 4 + nt) * 64 + l) * 4) = o[qt][nt];
        if (l < 16) smem[8192 + w * 16 + l] = lsum[qt];
        __syncthreads();
        if (w < 4) {
            f32x4 os = {0.f, 0.f, 0.f, 0.f}, ls = {0.f, 0.f, 0.f, 0.f};
            #pragma unroll
            for (int s = 0; s < 8; s++) {
                os += *(const f32x4*)(smem + ((s * 4 + w) * 64 + l) * 4);
                ls += *(const f32x4*)(smem + 8192 + s * 16 + quad * 4);
            }
            #pragma unroll
            for (int rr = 0; rr < 4; rr++)
                out[(bT + q0 + qt * 16 + quad * 4 + rr) * HS + w * 16 + c16] = os[rr] / ls[rr];
        }
    }
}

// ---------------------------------------------------------------------------
extern "C" void kernel_launch(void* const* d_in, const int* in_sizes, int n_in,
                              void* d_out, int out_size, void* d_ws, size_t ws_size,
                              hipStream_t stream) {
    const float* x  = (const float*)d_in[0];
    const float* Wq = (const float*)d_in[1];
    const float* Wk = (const float*)d_in[2];
    const float* Wv = (const float*)d_in[3];
    float* out = (float*)d_out;

    short* QKV = (short*)d_ws;
    short* Wt  = QKV + (size_t)3 * BT * HS;

    wtrans_kernel<<<768, 256, 0, stream>>>(Wq, Wk, Wv, Wt);
    proj_kernel<<<BT / 32, 512, 0, stream>>>(x, Wt, QKV);
    attn_kernel<<<512, 512, 0, stream>>>(QKV, out);
}